// Round 9
// baseline (258.273 us; speedup 1.0000x reference)
//
#include <hip/hip_runtime.h>

// NetVLAD fp32, N=64 HW=1024 D=512 K=64. bf16 MFMA.
// R14: true 2-phase double-buffered pipeline (T3/T14). Slab=64px so BOTH
// xbT and ab are double-buffered (2x64KB + 2x8KB = 144KB). Per P1 phase,
// each wave: issue 16 global loads (slab s) -> 16 LDS MFMAs of pass B
// (slab s-1) under the load latency -> consume+scatter+GEMM1. Pass A
// splits D across wave pairs (32px x 256d each); partials combined via the
// idle xbT buffer as f32 scratch. Loads stay in flight through the whole
// kernel -> attacks the measured MLP starvation (all pipes <30%, 2 TB/s).
//   kprep:  W[512][64] -> wt[64 k][512 d] bf16; zero a_sum/ssq.
//   kfused: grid 256=(n, 256px chunk), 4 slabs of 64px, pipelined.
//   kpost:  out = sum_4c vpart + a_sum*C; atomic ssq.
//   kscale: intra-norm (per n,k over d) x global L2 (per n), in place.

#define EPSF 1e-12f

typedef short bf16x8 __attribute__((ext_vector_type(8)));
typedef float f32x16 __attribute__((ext_vector_type(16)));

__device__ inline unsigned short f2bf_rne(float f) {
  union { float f; unsigned u; } v; v.f = f;
  unsigned u = v.u;
  unsigned r = u + 0x7fffu + ((u >> 16) & 1u);
  return (unsigned short)(r >> 16);
}
__device__ inline unsigned pk2(float a, float b) {
#if __has_builtin(__builtin_amdgcn_cvt_pk_bf16_f32)
  auto r = __builtin_amdgcn_cvt_pk_bf16_f32(a, b);
  return __builtin_bit_cast(unsigned, r);
#else
  return (unsigned)f2bf_rne(a) | ((unsigned)f2bf_rne(b) << 16);
#endif
}

// ---------------- K0: W transpose (blocks 0-7) + zero stats (block 8) ------
__global__ __launch_bounds__(256) void kprep(
    const float* __restrict__ Wm, unsigned short* __restrict__ wt,
    float* __restrict__ stats /* a_sum(4096) + ssq(4096) */) {
  const int t = threadIdx.x, bx = blockIdx.x;
  if (bx == 8) {
    float4 z = {0.f, 0.f, 0.f, 0.f};
#pragma unroll
    for (int r = 0; r < 8; ++r)
      *(float4*)&stats[(size_t)(r * 256 + t) * 4] = z;
    return;
  }
  __shared__ float tile[64][65];
  {
    int col = (t & 15) * 4, rbase = t >> 4;
#pragma unroll
    for (int r = 0; r < 4; ++r) {
      int row = rbase + 16 * r;
      *(float4*)&tile[row][col] =
          *(const float4*)&Wm[(size_t)(bx * 64 + row) * 64 + col];
    }
  }
  __syncthreads();
  int k = t >> 2, seg = (t & 3) * 16;
  size_t o = (size_t)k * 512 + bx * 64 + seg;
#pragma unroll
  for (int j = 0; j < 16; j += 2)
    *(unsigned*)&wt[o + j] = pk2(tile[seg + j][k], tile[seg + j + 1][k]);
}

// ---------------- fused assign + vlad, pipelined ---------------------------
// grid 256 = (n=bid>>2, chunk c=bid&3 of 256 px). 4 waves x 64 lanes.
// LDS: xbT[2][512 d][64 px] bf16 (2x64KB) + ab[2][64 k][64 px] (2x8KB).
// Wave roles: pair p=w>>1 owns px 32p..32p+31 of each slab; dhalf=(w&1)*256.
// Pass B: wave w owns d [128w,128w+128) x 64 k over the slab's 64 px.
__global__ __launch_bounds__(256, 1) void kfused(
    const float* __restrict__ x, const unsigned short* __restrict__ wt,
    const float* __restrict__ b, float* __restrict__ vpart,
    float* __restrict__ a_sum) {
  __shared__ unsigned short xbT[2][512 * 64];  // [d][px ^ ((d&7)<<3)]
  __shared__ unsigned short ab[2][64 * 64];    // [k][px ^ ((k&7)<<3)]
  const int t = threadIdx.x;
  const int w = t >> 6, lane = t & 63, l31 = lane & 31, h = lane >> 5;
  const int bid = blockIdx.x;
  const int n = bid >> 2, c = bid & 3;
  const int pxl = (w >> 1) * 32 + l31;       // local px (0..63) for pass A
  const int dhalf = (w & 1) * 256;           // this wave's GEMM1 d-range
  const unsigned short* wk0 = wt + (size_t)l31 * 512;
  const unsigned short* wk1 = wt + (size_t)(32 + l31) * 512;

  f32x16 accv[8];                            // pass B acc [dt 0..3][kt 0..1]
#pragma unroll
  for (int i = 0; i < 8; ++i)
#pragma unroll
    for (int j = 0; j < 16; ++j) accv[i][j] = 0.f;
  float sa0[16], sa1[16];                    // a_sum partials (odd waves use)
#pragma unroll
  for (int r = 0; r < 16; ++r) { sa0[r] = 0.f; sa1[r] = 0.f; }

#pragma unroll
  for (int s = 0; s < 4; ++s) {
    const int cur = s & 1, prv = (s + 1) & 1; // prv == (s-1)&1 == (s+1)&1
    const float* rowp =
        x + ((size_t)n * 1024 + c * 256 + s * 64 + pxl) * 512 + dhalf;
    f32x16 s0, s1;
#pragma unroll
    for (int i = 0; i < 16; ++i) { s0[i] = 0.f; s1[i] = 0.f; }

    // ---- P1: GEMM1(s) loads interleaved with pass B(s-1) LDS MFMAs ----
#pragma unroll
    for (int u = 0; u < 2; ++u) {
      float4 xs[16];
#pragma unroll
      for (int j = 0; j < 8; ++j) {          // issue 16 global loads
        const int kd = (u * 8 + j) * 16 + h * 8;   // rel to dhalf
        xs[2 * j]     = *(const float4*)&rowp[kd];
        xs[2 * j + 1] = *(const float4*)&rowp[kd + 4];
      }
      if (s > 0) {                           // B(s-1): 2 px-K-steps, 16 MFMA
#pragma unroll
        for (int ks = 2 * u; ks < 2 * u + 2; ++ks) {
          const int px0 = ks * 16 + h * 8;
          bf16x8 bb0 =
              *(const bf16x8*)&ab[prv][l31 * 64 + (px0 ^ ((l31 & 7) << 3))];
          bf16x8 bb1 = *(const bf16x8*)&ab[prv][(32 + l31) * 64 +
                                               (px0 ^ ((l31 & 7) << 3))];
#pragma unroll
          for (int dt = 0; dt < 4; ++dt) {
            const int dr = 128 * w + dt * 32 + l31;
            bf16x8 aa =
                *(const bf16x8*)&xbT[prv][dr * 64 + (px0 ^ ((dr & 7) << 3))];
            accv[dt * 2 + 0] = __builtin_amdgcn_mfma_f32_32x32x16_bf16(
                aa, bb0, accv[dt * 2 + 0], 0, 0, 0);
            accv[dt * 2 + 1] = __builtin_amdgcn_mfma_f32_32x32x16_bf16(
                aa, bb1, accv[dt * 2 + 1], 0, 0, 0);
          }
        }
      }
#pragma unroll
      for (int j = 0; j < 8; ++j) {          // consume: pk2+scatter+GEMM1
        const int kd = (u * 8 + j) * 16 + h * 8;
        union { unsigned uu[4]; bf16x8 v; } ax;
        ax.uu[0] = pk2(xs[2 * j].x, xs[2 * j].y);
        ax.uu[1] = pk2(xs[2 * j].z, xs[2 * j].w);
        ax.uu[2] = pk2(xs[2 * j + 1].x, xs[2 * j + 1].y);
        ax.uu[3] = pk2(xs[2 * j + 1].z, xs[2 * j + 1].w);
#pragma unroll
        for (int j2 = 0; j2 < 4; ++j2) {
          const int da = dhalf + kd + 2 * j2, db = da + 1;
          xbT[cur][da * 64 + (pxl ^ ((da & 7) << 3))] =
              (unsigned short)(ax.uu[j2] & 0xffffu);
          xbT[cur][db * 64 + (pxl ^ ((db & 7) << 3))] =
              (unsigned short)(ax.uu[j2] >> 16);
        }
        bf16x8 b0 = *(const bf16x8*)&wk0[dhalf + kd];
        bf16x8 b1 = *(const bf16x8*)&wk1[dhalf + kd];
        s0 = __builtin_amdgcn_mfma_f32_32x32x16_bf16(b0, ax.v, s0, 0, 0, 0);
        s1 = __builtin_amdgcn_mfma_f32_32x32x16_bf16(b1, ax.v, s1, 0, 0, 0);
      }
    }
    __syncthreads();
    // ---- P2a: even waves write D-half partials into idle xbT buffer ----
    float* scr = (float*)&xbT[prv][0];       // free: B(s-1) done, scatter(s+1) later
    if ((w & 1) == 0) {
      float* my = scr + (w >> 1) * 4096 + lane * 32;
#pragma unroll
      for (int r = 0; r < 16; ++r) { my[r] = s0[r]; my[16 + r] = s1[r]; }
    }
    __syncthreads();
    // ---- P2b: odd waves combine + lane-local softmax -> ab[cur] ----
    if (w & 1) {
      const float* my = scr + (w >> 1) * 4096 + lane * 32;
      float v0[16], v1[16];
      float m = -3.402823466e+38f;
#pragma unroll
      for (int r = 0; r < 16; ++r) {
        const int k0 = (r & 3) + 8 * (r >> 2) + 4 * h;
        v0[r] = s0[r] + my[r] + b[k0];
        v1[r] = s1[r] + my[16 + r] + b[k0 + 32];
        m = fmaxf(m, fmaxf(v0[r], v1[r]));
      }
      m = fmaxf(m, __shfl_xor(m, 32, 64));   // combine h-halves (same px)
      float a0[16], a1[16];
      float S = 0.f;
#pragma unroll
      for (int r = 0; r < 16; ++r) {
        a0[r] = __expf(v0[r] - m);
        a1[r] = __expf(v1[r] - m);
        S += a0[r] + a1[r];
      }
      S += __shfl_xor(S, 32, 64);
      const float inv = 1.0f / S;
#pragma unroll
      for (int r = 0; r < 16; ++r) {
        a0[r] *= inv; a1[r] *= inv;
        sa0[r] += a0[r]; sa1[r] += a1[r];
        const int k0 = (r & 3) + 8 * (r >> 2) + 4 * h, k1 = k0 + 32;
        ab[cur][k0 * 64 + (pxl ^ ((k0 & 7) << 3))] = f2bf_rne(a0[r]);
        ab[cur][k1 * 64 + (pxl ^ ((k1 & 7) << 3))] = f2bf_rne(a1[r]);
      }
    }
    __syncthreads();
  }
  // ---- epilogue: pass B for slab 3 (buffer 1), 4 px-K-steps ----
#pragma unroll
  for (int ks = 0; ks < 4; ++ks) {
    const int px0 = ks * 16 + h * 8;
    bf16x8 bb0 = *(const bf16x8*)&ab[1][l31 * 64 + (px0 ^ ((l31 & 7) << 3))];
    bf16x8 bb1 =
        *(const bf16x8*)&ab[1][(32 + l31) * 64 + (px0 ^ ((l31 & 7) << 3))];
#pragma unroll
    for (int dt = 0; dt < 4; ++dt) {
      const int dr = 128 * w + dt * 32 + l31;
      bf16x8 aa = *(const bf16x8*)&xbT[1][dr * 64 + (px0 ^ ((dr & 7) << 3))];
      accv[dt * 2 + 0] = __builtin_amdgcn_mfma_f32_32x32x16_bf16(
          aa, bb0, accv[dt * 2 + 0], 0, 0, 0);
      accv[dt * 2 + 1] = __builtin_amdgcn_mfma_f32_32x32x16_bf16(
          aa, bb1, accv[dt * 2 + 1], 0, 0, 0);
    }
  }
  // ---- a_sum: odd waves, ILP butterfly over px-lanes then atomics ----
  if (w & 1) {
#pragma unroll
    for (int msk = 1; msk < 32; msk <<= 1) {
#pragma unroll
      for (int r = 0; r < 16; ++r) {
        sa0[r] += __shfl_xor(sa0[r], msk, 64);
        sa1[r] += __shfl_xor(sa1[r], msk, 64);
      }
    }
    if (l31 < 16) {
      const int r = l31;
      const int k0 = (r & 3) + 8 * (r >> 2) + 4 * h;
      atomicAdd(&a_sum[n * 64 + k0], sa0[r]);
      atomicAdd(&a_sum[n * 64 + k0 + 32], sa1[r]);
    }
  }
  // ---- epilogue: plain-write this chunk's partial V [512][64] ----
  float* vp = vpart + (size_t)c * 2097152 + (size_t)n * 32768;
#pragma unroll
  for (int dt = 0; dt < 4; ++dt) {
#pragma unroll
    for (int kt = 0; kt < 2; ++kt) {
      const f32x16 a = accv[dt * 2 + kt];
      const int kcol = kt * 32 + l31;
#pragma unroll
      for (int r = 0; r < 16; ++r) {
        const int drow = 128 * w + dt * 32 + (r & 3) + 8 * (r >> 2) + 4 * h;
        vp[drow * 64 + kcol] = a[r];
      }
    }
  }
}

// ---------------- kpost: out = sum_c vpart + a_sum*C; atomic ssq -----------
__global__ __launch_bounds__(256) void kpost(
    const float* __restrict__ vpart, const float* __restrict__ a_sum,
    const float* __restrict__ C, float* __restrict__ out,
    float* __restrict__ ssq) {
  const int bid = blockIdx.x;               // 512: n fast for locality
  const int n = bid & 63, d0 = (bid >> 6) * 64;
  const int t = threadIdx.x, k = t & 63, dr = t >> 6;
  const float as = a_sum[n * 64 + k];
  const size_t nb = (size_t)n * 32768;
  float sq = 0.f;
#pragma unroll
  for (int r = 0; r < 16; ++r) {
    const int d = d0 + dr * 16 + r;
    const size_t idx = nb + (size_t)d * 64 + k;
    float o = as * C[(size_t)d * 64 + k];
#pragma unroll
    for (int cc = 0; cc < 4; ++cc) o += vpart[idx + (size_t)cc * 2097152];
    out[idx] = o;
    sq += o * o;
  }
  atomicAdd(&ssq[n * 64 + k], sq);
}

// ---------------- kscale: normalize in place -------------------------------
__global__ __launch_bounds__(256) void kscale(
    float* __restrict__ out, const float* __restrict__ ssq) {
  const int n = blockIdx.y, slice = blockIdx.x;
  const int t = threadIdx.x, k = t & 63, rg = t >> 6;
  __shared__ float sk[64];
  __shared__ float tot;
  if (t < 64) {
    float cc = ssq[n * 64 + t];
    sk[t] = rsqrtf(cc + EPSF);
    float contrib = cc / (cc + EPSF);
#pragma unroll
    for (int m = 32; m; m >>= 1) contrib += __shfl_xor(contrib, m, 64);
    if (t == 0) tot = rsqrtf(contrib + EPSF);
  }
  __syncthreads();
  const float scale = sk[k] * tot;
  float* vb = out + (size_t)n * 32768 + (size_t)slice * 4096;
#pragma unroll
  for (int r = rg; r < 64; r += 4) vb[r * 64 + k] *= scale;
}

extern "C" void kernel_launch(void* const* d_in, const int* in_sizes, int n_in,
                              void* d_out, int out_size, void* d_ws, size_t ws_size,
                              hipStream_t stream) {
  const float* x  = (const float*)d_in[0];   // [64,32,32,512]
  const float* Wm = (const float*)d_in[1];   // [512,64]
  const float* b  = (const float*)d_in[2];   // [64]
  const float* C  = (const float*)d_in[3];   // [512,64]
  float* out = (float*)d_out;                // [64, 32768]

  float* vpart = (float*)d_ws;                         // 32 MiB: 4 x [64][512][64]
  unsigned short* wt = (unsigned short*)(vpart + (size_t)4 * 2097152);  // 64 KiB
  float* stats = (float*)(wt + (size_t)64 * 512);      // a_sum 4096 + ssq 4096
  float* a_sum = stats;
  float* ssq   = stats + 4096;

  kprep<<<dim3(9), dim3(256), 0, stream>>>(Wm, wt, stats);
  kfused<<<dim3(256), dim3(256), 0, stream>>>(x, wt, b, vpart, a_sum);
  kpost<<<dim3(512), dim3(256), 0, stream>>>(vpart, a_sum, C, out, ssq);
  kscale<<<dim3(8, 64), dim3(256), 0, stream>>>(out, ssq);
}